// Round 1
// baseline (241.301 us; speedup 1.0000x reference)
//
#include <hip/hip_runtime.h>

typedef short short8 __attribute__((ext_vector_type(8)));
typedef float f32x4 __attribute__((ext_vector_type(4)));
typedef float f32x2 __attribute__((ext_vector_type(2)));

#define TB 8            // batch elements per group
#define NBG 4           // groups per block (sequential)
#define HALO 46         // halo positions stored per batch (pos -2 .. 43)
#define GSTRIDE 2216    // bf16 stride per batch in gtile: 8*odd, >= 46*48=2208 (bank-decorrelated)
#define NT 3            // N tiles (48 = 3*16, cols >=37 zero-padded)
#define MTILES 20       // (TB*40)/16 M tiles per group

__device__ __forceinline__ unsigned short f2bf(float f) {
    unsigned int u = __float_as_uint(f);
    u += 0x7fff + ((u >> 16) & 1);   // RNE
    return (unsigned short)(u >> 16);
}

__global__ __launch_bounds__(256, 2) void lorenz96_fused(
    const float* __restrict__ u,
    const float* __restrict__ coeff,
    const float* __restrict__ W1,
    const float* __restrict__ b1,
    const float* __restrict__ W2,
    const float* __restrict__ b2,
    const float* __restrict__ W3,
    const float* __restrict__ b3,
    float* __restrict__ out)
{
    // LDS budget: 35456 + 24576 + 2816 + 1280 = 64128 B  (<= 64 KiB)
    __shared__ __align__(16) unsigned short gtile[TB * GSTRIDE];     // gated hidden, bf16, [b][h][c] c-contig
    __shared__ __align__(16) unsigned short B_lds[NT * 8 * 64 * 8];  // W2 pre-swizzled to MFMA lane order
    __shared__ __align__(8)  f32x2 u_s2[TB * 44];                    // u_s2[b][j] = (u[j-2], u[j-1]) mod 40
    __shared__ float out1_s[TB * 40];                                // polynomial term per row m=p*8+b

    const int t = threadIdx.x;
    const int lane = t & 63;
    const int wave = t >> 6;

    // ---------- one-time stage 0a: B_lds fill (pre-swizzled W2, zero-padded K->256, N->48) ----------
    // B[k = tap*48 + c][o] = W2[o][c][tap];  lane holds B[ks*32 + quad*8 + j][nt*16 + (lane&15)]
    for (int g = t; g < NT * 8 * 64; g += 256) {
        int lg   = g & 63;
        int ks   = (g >> 6) & 7;
        int nt   = g >> 9;
        int o    = nt * 16 + (lg & 15);
        int kb   = ks * 32 + (lg >> 4) * 8;
        short8 pack;
        #pragma unroll
        for (int j = 0; j < 8; ++j) {
            int k = kb + j;
            float v = 0.f;
            if (k < 240 && o < 37) {
                int c = k % 48, tap = k / 48;
                v = W2[o * 240 + c * 5 + tap];
            }
            pack[j] = (short)f2bf(v);
        }
        *(short8*)&B_lds[g * 8] = pack;
    }

    // ---------- one-time stage 0b: per-thread W1/b1 registers (stage-1 role) ----------
    // thread -> (cg = channel-group of 8 g-channels [0..5], sl = position slot [0..41])
    const int cg = t % 6;
    const int sl = t / 6;
    const bool s1_active = (sl < 42);
    float w1a[8][5], b1a[8], w1b[8][5], b1b[8];
    if (s1_active) {
        #pragma unroll
        for (int j = 0; j < 8; ++j) {
            int co = cg * 8 + j;
            #pragma unroll
            for (int k = 0; k < 5; ++k) w1a[j][k] = W1[co * 5 + k];
            b1a[j] = b1[co];
            if (cg >= 3) {                    // gated channels: g[c] = h1[c]*h1[c+24]
                int co2 = co + 24;
                #pragma unroll
                for (int k = 0; k < 5; ++k) w1b[j][k] = W1[co2 * 5 + k];
                b1b[j] = b1[co2];
            }
        }
    }

    // epilogue constants (per-lane: 3 output-channel slots o = nt*16 + (lane&15))
    float w3v[NT], b2v[NT];
    #pragma unroll
    for (int nt = 0; nt < NT; ++nt) {
        int o = nt * 16 + (lane & 15);
        bool valid = (o < 37);
        w3v[nt] = valid ? W3[o] : 0.f;
        b2v[nt] = valid ? b2[o] : 0.f;
    }
    const float b3v = b3[0];
    float cf[18];                             // uniform -> scalar loads/SGPRs
    #pragma unroll
    for (int i = 0; i < 18; ++i) cf[i] = coeff[i];

    __syncthreads();   // B_lds ready

    // ---------- per-wave B fragments, held in registers for all groups ----------
    short8 bfrag[NT][8];
    #pragma unroll
    for (int nt = 0; nt < NT; ++nt)
        #pragma unroll
        for (int ks = 0; ks < 8; ++ks)
            bfrag[nt][ks] = *(const short8*)&B_lds[((nt * 8 + ks) * 64 + lane) * 8];

    const int b0_block = blockIdx.x * (TB * NBG);

    for (int grp = 0; grp < NBG; ++grp) {
        const int b0 = b0_block + grp * TB;

        __syncthreads();   // prior group's readers done before overwriting LDS

        // ---------- stage 0c: u staging (pairs for aligned b64 reads) ----------
        for (int idx = t; idx < TB * 44; idx += 256) {
            int b = idx / 44, j = idx % 44;
            float v0 = u[(b0 + b) * 40 + ((j + 38) % 40)];
            float v1 = u[(b0 + b) * 40 + ((j + 39) % 40)];
            f32x2 p; p[0] = v0; p[1] = v1;
            u_s2[idx] = p;
        }

        __syncthreads();   // u_s2 ready

        // ---------- polynomial term out1 per row (m = p*8 + b) ----------
        for (int m = t; m < TB * 40; m += 256) {
            int p = m >> 3, b = m & 7;
            f32x2 ua = u_s2[b * 44 + p];
            f32x2 ub = u_s2[b * 44 + p + 2];
            f32x2 uc = u_s2[b * 44 + p + 4];
            float um2 = ua[0], um1 = ua[1], u0 = ub[0], up1 = ub[1], up2 = uc[0];
            float r = cf[0] + cf[1]*um2 + cf[2]*um1 + cf[3]*u0 + cf[4]*up1 + cf[5]*up2
                    + cf[6]*um2*um2 + cf[7]*um1*um1 + cf[8]*u0*u0 + cf[9]*up1*up1 + cf[10]*up2*up2
                    + cf[11]*um2*um1 + cf[12]*um1*u0 + cf[13]*u0*up1 + cf[14]*up1*up2
                    + cf[15]*um2*u0 + cf[16]*um1*up1 + cf[17]*u0*up2;
            out1_s[m] = r;
        }

        // ---------- stage 1: conv1 + relu + GLU gating -> gtile (bf16) ----------
        if (s1_active) {
            for (int pos = sl; pos < TB * HALO; pos += 42) {
                int b = pos / 46, h = pos % 46;
                int pe = h - 2; if (pe < 0) pe += 40; if (pe >= 40) pe -= 40;  // effective position
                f32x2 ua = u_s2[b * 44 + pe];
                f32x2 ub = u_s2[b * 44 + pe + 2];
                f32x2 uc = u_s2[b * 44 + pe + 4];
                float uw[5] = {ua[0], ua[1], ub[0], ub[1], uc[0]};
                short8 gv;
                #pragma unroll
                for (int j = 0; j < 8; ++j) {
                    float a = b1a[j];
                    #pragma unroll
                    for (int k = 0; k < 5; ++k) a = fmaf(uw[k], w1a[j][k], a);
                    a = fmaxf(a, 0.f);
                    if (cg >= 3) {
                        float bb = b1b[j];
                        #pragma unroll
                        for (int k = 0; k < 5; ++k) bb = fmaf(uw[k], w1b[j][k], bb);
                        a *= fmaxf(bb, 0.f);
                    }
                    gv[j] = (short)f2bf(a);
                }
                *(short8*)&gtile[b * GSTRIDE + h * 48 + cg * 8] = gv;
            }
        }

        __syncthreads();   // gtile + out1_s ready

        // ---------- stage 2: MFMA GEMM (M=128? no: M=320 rows, m = p*8 + b) + fused epilogue ----------
        const int row_in = lane & 15;
        const int quad   = lane >> 4;
        #pragma unroll
        for (int i = 0; i < 5; ++i) {
            const int mt = wave + 4 * i;              // 4 waves x 5 = 20 M-tiles
            const int m  = mt * 16 + row_in;
            const int p  = m >> 3, b = m & 7;
            const unsigned short* abase = &gtile[b * GSTRIDE + p * 48 + quad * 8];
            short8 af[8];
            #pragma unroll
            for (int ks = 0; ks < 8; ++ks) af[ks] = *(const short8*)(abase + ks * 32);
            f32x4 acc0 = {0.f,0.f,0.f,0.f}, acc1 = {0.f,0.f,0.f,0.f}, acc2 = {0.f,0.f,0.f,0.f};
            #pragma unroll
            for (int ks = 0; ks < 8; ++ks) {
                acc0 = __builtin_amdgcn_mfma_f32_16x16x32_bf16(af[ks], bfrag[0][ks], acc0, 0, 0, 0);
                acc1 = __builtin_amdgcn_mfma_f32_16x16x32_bf16(af[ks], bfrag[1][ks], acc1, 0, 0, 0);
                acc2 = __builtin_amdgcn_mfma_f32_16x16x32_bf16(af[ks], bfrag[2][ks], acc2, 0, 0, 0);
            }
            // epilogue: relu(h2 + b2) . W3 folded per lane, then 16-lane butterfly sum
            float s[4];
            #pragma unroll
            for (int r = 0; r < 4; ++r) {
                s[r] = fmaxf(acc0[r] + b2v[0], 0.f) * w3v[0]
                     + fmaxf(acc1[r] + b2v[1], 0.f) * w3v[1]
                     + fmaxf(acc2[r] + b2v[2], 0.f) * w3v[2];
            }
            #pragma unroll
            for (int mask = 1; mask < 16; mask <<= 1) {
                #pragma unroll
                for (int r = 0; r < 4; ++r) s[r] += __shfl_xor(s[r], mask, 64);
            }
            const int c = lane & 15;
            if (c < 4) {   // 16 lanes store the tile's 16 rows
                int mo = mt * 16 + quad * 4 + c;
                int po = mo >> 3, bo = mo & 7;
                out[(b0 + bo) * 40 + po] = s[c] + b3v + out1_s[mo];
            }
        }
    }
}

extern "C" void kernel_launch(void* const* d_in, const int* in_sizes, int n_in,
                              void* d_out, int out_size, void* d_ws, size_t ws_size,
                              hipStream_t stream) {
    // inputs: 0=t(unused), 1=u, 2=coeff, 3=W1, 4=b1, 5=W2, 6=b2, 7=W3, 8=b3
    const float* u     = (const float*)d_in[1];
    const float* coeff = (const float*)d_in[2];
    const float* W1    = (const float*)d_in[3];
    const float* b1    = (const float*)d_in[4];
    const float* W2    = (const float*)d_in[5];
    const float* b2    = (const float*)d_in[6];
    const float* W3    = (const float*)d_in[7];
    const float* b3    = (const float*)d_in[8];
    float* out = (float*)d_out;

    const int n_batch = in_sizes[1] / 40;            // 65536
    const int grid = n_batch / (TB * NBG);           // 2048 blocks
    lorenz96_fused<<<grid, 256, 0, stream>>>(u, coeff, W1, b1, W2, b2, W3, b3, out);
}

// Round 3
// 223.433 us; speedup vs baseline: 1.0800x; 1.0800x over previous
//
#include <hip/hip_runtime.h>

typedef short s16x8 __attribute__((ext_vector_type(8)));
typedef short s16x4 __attribute__((ext_vector_type(4)));
typedef float f32x4 __attribute__((ext_vector_type(4)));

#define TB 8            // batch elements per group
#define NBG 4           // groups per block (sequential)
#define HALO 46         // halo positions stored per batch (pos -2 .. 43)
#define GSTRIDE 2216    // bf16 stride per batch in gtile (8*odd multiple: bank-decorrelated)
#define NT 3            // N tiles for stage-2 (48 cols, >=37 zero-padded)
#define GT_BYTES (TB * GSTRIDE * 2)          // 35456
#define BL_BYTES (NT * 8 * 64 * 8 * 2)       // 24576  (W2 staging, dead after init)
#define UB_SHORTS (384 * 8)                  // conv1 B-operand taps: 384 cols x 8 k-slots

__device__ __forceinline__ unsigned short f2bf(float f) {
    unsigned int u = __float_as_uint(f);
    u += 0x7fff + ((u >> 16) & 1);   // RNE
    return (unsigned short)(u >> 16);
}

__global__ __launch_bounds__(256, 2) void lorenz96_fused(
    const float* __restrict__ u,
    const float* __restrict__ coeff,
    const float* __restrict__ W1,
    const float* __restrict__ b1,
    const float* __restrict__ W2,
    const float* __restrict__ b2,
    const float* __restrict__ W3,
    const float* __restrict__ b3,
    float* __restrict__ out)
{
    // LDS: gtile | {B_lds (init only)  ALIASED WITH  u_b + out1_s (per-group)}
    // total = 35456 + 24576 = 60032 B  -> 2 blocks/CU (LDS-bound)
    __shared__ __align__(16) unsigned char smem[GT_BYTES + BL_BYTES];
    unsigned short* gtile  = (unsigned short*)smem;
    unsigned short* B_lds  = (unsigned short*)(smem + GT_BYTES);
    unsigned short* u_b    = (unsigned short*)(smem + GT_BYTES);             // aliases B_lds
    float*          out1_s = (float*)(smem + GT_BYTES + UB_SHORTS * 2);      // 320 floats

    const int t    = threadIdx.x;
    const int lane = t & 63;
    const int wave = t >> 6;
    const int quad = lane >> 4;
    const int l15  = lane & 15;

    // ---------- init 0a: W2 staging, pre-swizzled to MFMA fragment order ----------
    // W2eff[o][k = tap*48 + c] = W2[o][c][tap]; fragment: lane holds [o = nt*16 + l15][k = ks*32 + quad*8 + j]
    for (int g = t; g < NT * 8 * 64; g += 256) {
        int lg = g & 63;
        int ks = (g >> 6) & 7;
        int nt = g >> 9;
        int o  = nt * 16 + (lg & 15);
        int kb = ks * 32 + (lg >> 4) * 8;
        s16x8 pack = {0, 0, 0, 0, 0, 0, 0, 0};
        #pragma unroll
        for (int j = 0; j < 8; ++j) {
            int k = kb + j;
            if (k < 240 && o < 37) {
                int c = k % 48, tap = k / 48;
                pack[j] = (short)f2bf(W2[o * 240 + c * 5 + tap]);
            }
        }
        *(s16x8*)&B_lds[g * 8] = pack;
    }

    // ---------- init 0b: conv1 A-fragments (W1 + fused b1 at k=5), register-resident ----------
    // channel row map (16 rows per tile): T0=ch0-15, T1=ch16-31, T2=ch32-47,
    // T3: rows 8-15 = ch48-55 (rows 0-7 zero-pad), T4 = ch56-71.
    // GLU pairing: T1 rows 8-15 (ch24-31) gate with T3 rows 8-15 (ch48-55);
    //              T2 (ch32-47) gates with T4 (ch56-71) -- same (quad,reg), in-lane.
    s16x8 aW1[5];
    {
        int chs[5];
        chs[0] = l15; chs[1] = 16 + l15; chs[2] = 32 + l15;
        chs[3] = (l15 >= 8) ? 40 + l15 : -1;
        chs[4] = 56 + l15;
        #pragma unroll
        for (int mt = 0; mt < 5; ++mt) {
            s16x8 a = {0, 0, 0, 0, 0, 0, 0, 0};
            int ch = chs[mt];
            if (quad == 0 && ch >= 0) {
                #pragma unroll
                for (int j = 0; j < 5; ++j) a[j] = (short)f2bf(W1[ch * 5 + j]);
                a[5] = (short)f2bf(b1[ch]);   // bias slot; B supplies 1.0 at k=5
            }
            aW1[mt] = a;
        }
    }

    // ---------- init 0c: epilogue constants (stage-2 C rows = output channels) ----------
    float w3v[NT][4], b2v[NT][4];
    #pragma unroll
    for (int nt = 0; nt < NT; ++nt)
        #pragma unroll
        for (int r = 0; r < 4; ++r) {
            int o = nt * 16 + quad * 4 + r;
            bool valid = (o < 37);
            w3v[nt][r] = valid ? W3[o] : 0.f;
            b2v[nt][r] = valid ? b2[o] : 0.f;
        }
    const float b3v = b3[0];
    float cf[18];
    #pragma unroll
    for (int i = 0; i < 18; ++i) cf[i] = coeff[i];

    __syncthreads();   // B_lds ready

    // stage-2 A-fragments (W2), register-resident for whole kernel
    s16x8 aW2[NT][8];
    #pragma unroll
    for (int nt = 0; nt < NT; ++nt)
        #pragma unroll
        for (int ks = 0; ks < 8; ++ks)
            aW2[nt][ks] = *(const s16x8*)&B_lds[((nt * 8 + ks) * 64 + lane) * 8];

    const int b0_block = blockIdx.x * (TB * NBG);

    for (int grp = 0; grp < NBG; ++grp) {
        const int b0 = b0_block + grp * TB;

        __syncthreads();   // prior group's readers done; B_lds reads done (grp 0)

        // ---------- phase 1a: conv1 B-operand taps -> u_b  (col = (b,h): b=col&7, h=col>>3) ----------
        for (int col = t; col < 384; col += 256) {
            s16x8 pk = {0, 0, 0, 0, 0, 0, 0, 0};
            if (col < 368) {
                int b = col & 7, h = col >> 3;
                const float* ur = u + (size_t)(b0 + b) * 40;
                #pragma unroll
                for (int j = 0; j < 5; ++j) {
                    int idx = h + 36 + j;              // (h-2)-2+j mod 40, biased +40
                    idx -= (idx >= 40) ? 40 : 0;
                    idx -= (idx >= 40) ? 40 : 0;
                    pk[j] = (short)f2bf(ur[idx]);
                }
                pk[5] = (short)0x3F80;                 // 1.0 -> multiplies the b1 slot
            }
            *(s16x8*)&u_b[col * 8] = pk;
        }

        // ---------- phase 1b: polynomial term per stage-2 row m = p*8 + b ----------
        for (int m = t; m < TB * 40; m += 256) {
            int p = m >> 3, b = m & 7;
            const float* ur = u + (size_t)(b0 + b) * 40;
            int i0 = p + 38; i0 -= (i0 >= 40) ? 40 : 0;
            int i1 = p + 39; i1 -= (i1 >= 40) ? 40 : 0;
            int i3 = p + 1;  i3 -= (i3 >= 40) ? 40 : 0;
            int i4 = p + 2;  i4 -= (i4 >= 40) ? 40 : 0;
            float um2 = ur[i0], um1 = ur[i1], u0 = ur[p], up1 = ur[i3], up2 = ur[i4];
            float r = cf[0] + cf[1]*um2 + cf[2]*um1 + cf[3]*u0 + cf[4]*up1 + cf[5]*up2
                    + cf[6]*um2*um2 + cf[7]*um1*um1 + cf[8]*u0*u0 + cf[9]*up1*up1 + cf[10]*up2*up2
                    + cf[11]*um2*um1 + cf[12]*um1*u0 + cf[13]*u0*up1 + cf[14]*up1*up2
                    + cf[15]*um2*u0 + cf[16]*um1*up1 + cf[17]*u0*up2;
            out1_s[m] = r;
        }

        __syncthreads();   // u_b ready

        // ---------- phase 2: conv1 via MFMA + in-lane GLU gating -> gtile ----------
        #pragma unroll
        for (int i = 0; i < 6; ++i) {
            const int ct  = wave + 4 * i;              // 24 col-tiles (384 cols, 368 live)
            const int col = ct * 16 + l15;
            s16x8 bU = {0, 0, 0, 0, 0, 0, 0, 0};
            if (quad == 0) bU = *(const s16x8*)&u_b[col * 8];
            f32x4 a0 = {0.f,0.f,0.f,0.f}, a1 = a0, a2 = a0, a3 = a0, a4 = a0;
            a0 = __builtin_amdgcn_mfma_f32_16x16x32_bf16(aW1[0], bU, a0, 0, 0, 0);
            a1 = __builtin_amdgcn_mfma_f32_16x16x32_bf16(aW1[1], bU, a1, 0, 0, 0);
            a2 = __builtin_amdgcn_mfma_f32_16x16x32_bf16(aW1[2], bU, a2, 0, 0, 0);
            a3 = __builtin_amdgcn_mfma_f32_16x16x32_bf16(aW1[3], bU, a3, 0, 0, 0);
            a4 = __builtin_amdgcn_mfma_f32_16x16x32_bf16(aW1[4], bU, a4, 0, 0, 0);
            const int b = col & 7, h = col >> 3;
            if (h < HALO) {
                s16x4 w0, w1, w2;
                #pragma unroll
                for (int r = 0; r < 4; ++r) {
                    float v0 = fmaxf(a0[r], 0.f);
                    float v1 = fmaxf(a1[r], 0.f);
                    if (quad >= 2) v1 *= fmaxf(a3[r], 0.f);     // ch24-31 gate
                    float v2 = fmaxf(a2[r], 0.f) * fmaxf(a4[r], 0.f);  // ch32-47 gate
                    w0[r] = (short)f2bf(v0);
                    w1[r] = (short)f2bf(v1);
                    w2[r] = (short)f2bf(v2);
                }
                unsigned short* gp = &gtile[b * GSTRIDE + h * 48 + quad * 4];
                *(s16x4*)(gp)      = w0;   // ch quad*4 .. +3
                *(s16x4*)(gp + 16) = w1;   // ch 16 + ...
                *(s16x4*)(gp + 32) = w2;   // ch 32 + ...
            }
        }

        __syncthreads();   // gtile + out1_s ready

        // ---------- phase 3: stage-2 GEMM, transposed (A=W2, B=G) + fused epilogue ----------
        #pragma unroll
        for (int i = 0; i < 5; ++i) {
            const int mt = wave + 4 * i;               // 20 M-tiles (320 G-rows)
            const int m  = mt * 16 + l15;
            const int p  = m >> 3, b = m & 7;
            const unsigned short* gbase = &gtile[b * GSTRIDE + p * 48 + quad * 8];
            s16x8 bg[8];
            #pragma unroll
            for (int ks = 0; ks < 8; ++ks) bg[ks] = *(const s16x8*)(gbase + ks * 32);
            f32x4 c0 = {0.f,0.f,0.f,0.f}, c1 = c0, c2 = c0;
            #pragma unroll
            for (int ks = 0; ks < 8; ++ks) {
                c0 = __builtin_amdgcn_mfma_f32_16x16x32_bf16(aW2[0][ks], bg[ks], c0, 0, 0, 0);
                c1 = __builtin_amdgcn_mfma_f32_16x16x32_bf16(aW2[1][ks], bg[ks], c1, 0, 0, 0);
                c2 = __builtin_amdgcn_mfma_f32_16x16x32_bf16(aW2[2][ks], bg[ks], c2, 0, 0, 0);
            }
            // epilogue: sum over output channels o (rows) of relu(h2+b2)*W3[o]
            float s = 0.f;
            #pragma unroll
            for (int r = 0; r < 4; ++r) {
                s += fmaxf(c0[r] + b2v[0][r], 0.f) * w3v[0][r];
                s += fmaxf(c1[r] + b2v[1][r], 0.f) * w3v[1][r];
                s += fmaxf(c2[r] + b2v[2][r], 0.f) * w3v[2][r];
            }
            s += __shfl_xor(s, 16, 64);                // sum across the 4 quads
            s += __shfl_xor(s, 32, 64);
            if (lane < 16) {
                int mo = mt * 16 + lane;
                out[(size_t)(b0 + (mo & 7)) * 40 + (mo >> 3)] = s + b3v + out1_s[mo];
            }
        }
    }
}

extern "C" void kernel_launch(void* const* d_in, const int* in_sizes, int n_in,
                              void* d_out, int out_size, void* d_ws, size_t ws_size,
                              hipStream_t stream) {
    // inputs: 0=t(unused), 1=u, 2=coeff, 3=W1, 4=b1, 5=W2, 6=b2, 7=W3, 8=b3
    const float* u     = (const float*)d_in[1];
    const float* coeff = (const float*)d_in[2];
    const float* W1    = (const float*)d_in[3];
    const float* b1    = (const float*)d_in[4];
    const float* W2    = (const float*)d_in[5];
    const float* b2    = (const float*)d_in[6];
    const float* W3    = (const float*)d_in[7];
    const float* b3    = (const float*)d_in[8];
    float* out = (float*)d_out;

    const int n_batch = in_sizes[1] / 40;            // 65536
    const int grid = n_batch / (TB * NBG);           // 2048 blocks
    lorenz96_fused<<<grid, 256, 0, stream>>>(u, coeff, W1, b1, W2, b2, W3, b3, out);
}